// Round 1
// baseline (284.868 us; speedup 1.0000x reference)
//
#include <hip/hip_runtime.h>

// out[s,d,b, i*32 + j] = x[2s, d, b, i] + x[2s+1, d, b, j]
// x: [128,16,64,32] f32 (16 MiB), out: [64,16,64,1024] f32 (256 MiB).
// Pure write-BW-bound outer-sum. float4 stores, grid-stride, input via L1/L2.

#define OUT_ELEMS  (64 * 16 * 64 * 1024)   // 67,108,864
#define OUT_F4     (OUT_ELEMS / 4)         // 16,777,216

__global__ __launch_bounds__(256) void dense_product_kernel(
    const float* __restrict__ x, float* __restrict__ out) {
    const int stride = gridDim.x * blockDim.x;
    for (int idx4 = blockIdx.x * blockDim.x + threadIdx.x; idx4 < OUT_F4;
         idx4 += stride) {
        // Each output row (s,d,b) = 1024 floats = 256 float4s.
        const int row    = idx4 >> 8;          // s*1024 + d*64 + b
        const int within = idx4 & 255;         // float4 index within row
        const int i      = within >> 3;        // 0..31 (left-factor index)
        const int j0     = (within & 7) << 2;  // 0,4,...,28 (right-factor base)

        // x flat base for factor 0 of this row: ((2s)*1024 + d*64 + b) * 32
        //   = (row + s*1024) * 32, with s*1024 = row & ~1023.
        const int abase = (row + (row & ~1023)) << 5;

        const float  a  = x[abase + i];
        const float4 bv = *reinterpret_cast<const float4*>(x + abase + 32768 + j0);

        float4 o;
        o.x = a + bv.x;
        o.y = a + bv.y;
        o.z = a + bv.z;
        o.w = a + bv.w;
        reinterpret_cast<float4*>(out)[idx4] = o;
    }
}

extern "C" void kernel_launch(void* const* d_in, const int* in_sizes, int n_in,
                              void* d_out, int out_size, void* d_ws, size_t ws_size,
                              hipStream_t stream) {
    const float* x   = (const float*)d_in[0];
    float*       out = (float*)d_out;
    // 2048 blocks x 256 threads, 32 float4-iterations each (memory-bound G11).
    dense_product_kernel<<<2048, 256, 0, stream>>>(x, out);
}

// Round 3
// 283.402 us; speedup vs baseline: 1.0052x; 1.0052x over previous
//
#include <hip/hip_runtime.h>

// out[s,d,b, i*32 + j] = x[2s, d, b, i] + x[2s+1, d, b, j]
// x: [128,16,64,32] f32 (16 MiB), out: [64,16,64,1024] f32 (256 MiB).
// Write-BW-bound outer-sum. Each block owns 32 contiguous output rows
// (128 KiB). Row r = s*1024 + d*64 + b; factor-0 input base (floats) is
// (r + (r & ~1023)) * 32, factor-1 is +32768. All 32 rows of a block share
// the same s (32 | 1024), so the base walks by 32 floats per row.

typedef float f32x4 __attribute__((ext_vector_type(4)));  // native clang vec
                                                          // (nontemporal ok)

#define ROWS_TOTAL     65536   // S*D*B = 64*16*64
#define ROWS_PER_BLOCK 32
#define NBLOCKS        (ROWS_TOTAL / ROWS_PER_BLOCK)  // 2048

__global__ __launch_bounds__(256) void dense_product_kernel(
    const float* __restrict__ x, float* __restrict__ out) {
    const int bid = blockIdx.x;
    const int tid = threadIdx.x;

    const int r0    = bid * ROWS_PER_BLOCK;      // first row of this block
    const int sbase = (r0 >> 10) << 10;          // s*1024 (block-uniform)
    const int abase = (r0 + sbase) << 5;         // factor-0 flat float index

    const int i  = tid >> 3;                     // 0..31, loop-invariant
    const int j0 = (tid & 7) << 2;               // 0,4,..,28, loop-invariant

    const float* __restrict__ pa = x + abase + i;
    const float* __restrict__ pb = x + abase + 32768 + j0;
    float* __restrict__ po = out + (size_t)r0 * 1024 + tid * 4;

#pragma unroll
    for (int k = 0; k < ROWS_PER_BLOCK; ++k) {
        const float a  = pa[k * 32];
        const f32x4 bv = *reinterpret_cast<const f32x4*>(pb + k * 32);
        f32x4 o = bv + a;  // broadcast add
        __builtin_nontemporal_store(o, reinterpret_cast<f32x4*>(po + k * 1024));
    }
}

extern "C" void kernel_launch(void* const* d_in, const int* in_sizes, int n_in,
                              void* d_out, int out_size, void* d_ws, size_t ws_size,
                              hipStream_t stream) {
    const float* x   = (const float*)d_in[0];
    float*       out = (float*)d_out;
    dense_product_kernel<<<NBLOCKS, 256, 0, stream>>>(x, out);
}